// Round 7
// baseline (36.456 us; speedup 1.0000x reference)
//
#include <hip/hip_runtime.h>
#include <hip/hip_bf16.h>

// out[8192,1024] = x[8192,1024] @ W[1024,1024]^T + b  (fp32 in/out, bf16 MFMA)
// v7: v5 geometry (BM=256 x BN=128, BK=32, 512 thr / 8 waves as 4Mx2N 64x64,
// grid 256 = 1 block/CU, XCD-exclusive m-panels, zero-conflict swizzle) with
// T4 raw-barrier discipline: NO __syncthreads vmcnt(0) drain in the main loop.
// Per K-tile: issue tile kt+2 global loads (stay in flight across barriers),
// ds_read frags, cvt+ds_write tile kt+1 (counted vmcnt by construction),
// setprio(1) 16-MFMA cluster, lgkmcnt(0) + raw s_barrier. b128 staging writes.

typedef float f32x4 __attribute__((ext_vector_type(4)));
typedef __bf16 bf16x8 __attribute__((ext_vector_type(8)));
typedef unsigned short u16x8 __attribute__((ext_vector_type(8)));

#define MD 8192
#define ND 1024
#define KD 1024
#define BM 256
#define BN 128
#define BK 32
#define NT (KD / BK)     // 32 K-tiles
#define THREADS 512

__device__ __forceinline__ u16x8 cvt8(f32x4 lo, f32x4 hi) {
  u16x8 o;
#pragma unroll
  for (int j = 0; j < 4; ++j) {
    o[j]     = __builtin_bit_cast(unsigned short, (__bf16)lo[j]);
    o[4 + j] = __builtin_bit_cast(unsigned short, (__bf16)hi[j]);
  }
  return o;
}

// Barrier cluster: fence LDS ops at IR + machine level, raw s_barrier (no vmcnt drain).
#define TILE_BARRIER()                                   \
  do {                                                   \
    asm volatile("s_waitcnt lgkmcnt(0)" ::: "memory");   \
    __builtin_amdgcn_sched_barrier(0);                   \
    __builtin_amdgcn_s_barrier();                        \
    __builtin_amdgcn_sched_barrier(0);                   \
  } while (0)

__global__ __launch_bounds__(THREADS, 2)
void linear_mfma_v7(const float* __restrict__ X, const float* __restrict__ W,
                    const float* __restrict__ Bv, float* __restrict__ C) {
  // 16-row stripes of 1024B; 16B slot (row,ks): byte = ((ks<<8)+((row&15)<<4)) ^ (ks<<5)
  // within stripe row>>4. Verified conflict-free (v3..v6: SQ_LDS_BANK_CONFLICT = 0).
  __shared__ __align__(16) char Asm[2][BM * BK * 2];   // 16 KB each
  __shared__ __align__(16) char Bsm[2][BN * BK * 2];   // 8 KB each

  const int bid = blockIdx.x;
  const int xcd = bid & 7;                 // dispatch round-robins XCDs by bid&7
  const int ord = bid >> 3;                // 0..31
  const int mtile = xcd * 4 + (ord >> 3);  // 4 XCD-exclusive m-panels per XCD
  const int ntile = ord & 7;
  const int brow = mtile * BM;
  const int bcol = ntile * BN;

  const int t = threadIdx.x;
  const int lane = t & 63;
  const int w = t >> 6;      // 0..7
  const int wm = w >> 1;     // 0..3 : 64-row quarter of BM=256
  const int wn = w & 1;      // 0..1 : 64-col half of BN=128

  // ---- staging map: thread owns 16B k-slot `ts = t&3` (k = ts*8..ts*8+7) of rows
  // A: rows (t>>2) and (t>>2)+128 ; B: row (t>>2) & 127 (t>>2 < 128 since B uses all 512 thr once)
  const int srow = t >> 2;   // 0..127
  const int ts = t & 3;      // 16B slot in k

  const float* gA0 = X + (size_t)(brow + srow) * KD + ts * 8;
  const float* gA1 = X + (size_t)(brow + srow + 128) * KD + ts * 8;
  const float* gB0 = W + (size_t)(bcol + srow) * KD + ts * 8;

  const int swz = (((ts << 8) + ((srow & 15) << 4)) ^ (ts << 5));
  const int woffA0 = (srow >> 4) * 1024 + swz;
  const int woffA1 = ((srow >> 4) + 8) * 1024 + swz;
  const int woffB0 = (srow >> 4) * 1024 + swz;

  // fragment read offset within a 1KB stripe (16B/lane, swizzle-mirrored; verified)
  const int fr = (lane * 16) ^ ((lane >> 4) << 5);

  // depth-2 prefetch register sets (static names only)
  f32x4 a0lo0, a0hi0, a1lo0, a1hi0, blo0, bhi0;   // set 0
  f32x4 a0lo1, a0hi1, a1lo1, a1hi1, blo1, bhi1;   // set 1

#define LOADSET0(kt)                                            \
  do {                                                          \
    const float* pA0 = gA0 + (size_t)(kt) * BK;                 \
    const float* pA1 = gA1 + (size_t)(kt) * BK;                 \
    const float* pB0 = gB0 + (size_t)(kt) * BK;                 \
    a0lo0 = *(const f32x4*)(pA0);  a0hi0 = *(const f32x4*)(pA0 + 4); \
    a1lo0 = *(const f32x4*)(pA1);  a1hi0 = *(const f32x4*)(pA1 + 4); \
    blo0  = *(const f32x4*)(pB0);  bhi0  = *(const f32x4*)(pB0 + 4); \
  } while (0)
#define LOADSET1(kt)                                            \
  do {                                                          \
    const float* pA0 = gA0 + (size_t)(kt) * BK;                 \
    const float* pA1 = gA1 + (size_t)(kt) * BK;                 \
    const float* pB0 = gB0 + (size_t)(kt) * BK;                 \
    a0lo1 = *(const f32x4*)(pA0);  a0hi1 = *(const f32x4*)(pA0 + 4); \
    a1lo1 = *(const f32x4*)(pA1);  a1hi1 = *(const f32x4*)(pA1 + 4); \
    blo1  = *(const f32x4*)(pB0);  bhi1  = *(const f32x4*)(pB0 + 4); \
  } while (0)

#define WRITESET0(buf)                                          \
  do {                                                          \
    *(u16x8*)&Asm[buf][woffA0] = cvt8(a0lo0, a0hi0);            \
    *(u16x8*)&Asm[buf][woffA1] = cvt8(a1lo0, a1hi0);            \
    *(u16x8*)&Bsm[buf][woffB0] = cvt8(blo0, bhi0);              \
  } while (0)
#define WRITESET1(buf)                                          \
  do {                                                          \
    *(u16x8*)&Asm[buf][woffA0] = cvt8(a0lo1, a0hi1);            \
    *(u16x8*)&Asm[buf][woffA1] = cvt8(a1lo1, a1hi1);            \
    *(u16x8*)&Bsm[buf][woffB0] = cvt8(blo1, bhi1);              \
  } while (0)

  f32x4 acc[4][4] = {};

#define COMPUTE(buf)                                                           \
  do {                                                                         \
    bf16x8 bf[4];                                                              \
    _Pragma("unroll") for (int n = 0; n < 4; ++n)                              \
      bf[n] = __builtin_bit_cast(bf16x8,                                       \
          *(const u16x8*)(&Bsm[buf][(wn * 4 + n) * 1024 + fr]));               \
    bf16x8 am[4];                                                              \
    _Pragma("unroll") for (int m = 0; m < 4; ++m)                              \
      am[m] = __builtin_bit_cast(bf16x8,                                       \
          *(const u16x8*)(&Asm[buf][(wm * 4 + m) * 1024 + fr]));               \
    __builtin_amdgcn_s_setprio(1);                                             \
    _Pragma("unroll") for (int m = 0; m < 4; ++m)                              \
      _Pragma("unroll") for (int n = 0; n < 4; ++n)                            \
        acc[m][n] = __builtin_amdgcn_mfma_f32_16x16x32_bf16(am[m], bf[n],      \
                                                            acc[m][n], 0, 0, 0); \
    __builtin_amdgcn_s_setprio(0);                                             \
  } while (0)

  // ---- prologue: set0 <- tile0, set1 <- tile1, stage tile0 -> buf0, barrier
  LOADSET0(0);
  LOADSET1(1);
  WRITESET0(0);          // cvt waits counted vmcnt (set1's 6 loads stay in flight)
  TILE_BARRIER();

  // ---- main loop: 2 K-tiles per iteration, ONE raw barrier per tile, vmcnt never drained
#pragma unroll 1
  for (int kt2 = 0; kt2 < NT / 2; ++kt2) {
    // EVEN tile kt = 2*kt2 : reads buf0; set0 free -> prefetch tile kt+2
    if (kt2 < NT / 2 - 1) LOADSET0(2 * kt2 + 2);
    WRITESET1(1);                          // stage tile kt+1 -> buf1 (counted vmcnt)
    COMPUTE(0);
    TILE_BARRIER();                        // lgkmcnt(0) + s_barrier (loads stay in flight)

    // ODD tile kt = 2*kt2+1 : reads buf1; set1 free -> prefetch tile kt+3
    if (kt2 < NT / 2 - 1) LOADSET1(2 * kt2 + 3);
    if (kt2 < NT / 2 - 1) WRITESET0(0);    // stage tile kt+2 -> buf0
    COMPUTE(1);
    TILE_BARRIER();
  }

  // ---- epilogue: C/D layout col = lane&15, row = (lane>>4)*4 + j  [m89, validated v5]
  const int rbase = brow + wm * 64 + ((lane >> 4) << 2);
  const int cbase = bcol + wn * 64 + (lane & 15);
#pragma unroll
  for (int n = 0; n < 4; ++n) {
    const int col = cbase + n * 16;
    const float bv = Bv[col];
#pragma unroll
    for (int m = 0; m < 4; ++m) {
      const int row = rbase + m * 16;
#pragma unroll
      for (int j = 0; j < 4; ++j) {
        C[(size_t)(row + j) * ND + col] = acc[m][n][j] + bv;
      }
    }
  }
}

extern "C" void kernel_launch(void* const* d_in, const int* in_sizes, int n_in,
                              void* d_out, int out_size, void* d_ws, size_t ws_size,
                              hipStream_t stream) {
  const float* x = (const float*)d_in[0];   // [8192,1024] f32
  const float* W = (const float*)d_in[1];   // [1024,1024] f32
  const float* b = (const float*)d_in[2];   // [1024] f32
  float* out = (float*)d_out;               // [8192,1024] f32

  dim3 grid((MD / BM) * (ND / BN));   // 32 * 8 = 256 blocks = 1 per CU
  dim3 block(THREADS);
  hipLaunchKernelGGL(linear_mfma_v7, grid, block, 0, stream, x, W, b, out);
}

// Round 8
// 35.026 us; speedup vs baseline: 1.0408x; 1.0408x over previous
//
#include <hip/hip_runtime.h>
#include <hip/hip_bf16.h>

// out[8192,1024] = x[8192,1024] @ W[1024,1024]^T + b  (fp32 in/out, bf16 MFMA)
// v8: BM=256 x BN=128, BK=64 (16 K-tiles, ~1200cyc each), 512 thr / 8 waves as
// 4Mx2N 64x64. True 1-tile prefetch distance (> HBM miss latency): loads for
// tile kt+2 issued at tile kt, consumed (cvt+ds_write) at tile kt+1. Raw
// lgkmcnt(0)+s_barrier per tile (16 barriers, vmcnt never drained -> counted
// vmcnt(12) at cvt). v4-verified BK=64 zero-conflict swizzle. Grid 256 = 1
// block/CU, XCD-exclusive m-panels. setprio around MFMA cluster.

typedef float f32x4 __attribute__((ext_vector_type(4)));
typedef __bf16 bf16x8 __attribute__((ext_vector_type(8)));
typedef unsigned short u16x8 __attribute__((ext_vector_type(8)));

#define MD 8192
#define ND 1024
#define KD 1024
#define BM 256
#define BN 128
#define BK 64
#define NT (KD / BK)     // 16 K-tiles
#define THREADS 512

__device__ __forceinline__ u16x8 cvt8(f32x4 lo, f32x4 hi) {
  u16x8 o;
#pragma unroll
  for (int j = 0; j < 4; ++j) {
    o[j]     = __builtin_bit_cast(unsigned short, (__bf16)lo[j]);
    o[4 + j] = __builtin_bit_cast(unsigned short, (__bf16)hi[j]);
  }
  return o;
}

// raw barrier: LDS completion only; outstanding global loads stay in flight
#define TILE_BARRIER()                                   \
  do {                                                   \
    asm volatile("s_waitcnt lgkmcnt(0)" ::: "memory");   \
    __builtin_amdgcn_sched_barrier(0);                   \
    __builtin_amdgcn_s_barrier();                        \
    __builtin_amdgcn_sched_barrier(0);                   \
  } while (0)

__global__ __launch_bounds__(THREADS, 2)
void linear_mfma_v8(const float* __restrict__ X, const float* __restrict__ W,
                    const float* __restrict__ Bv, float* __restrict__ C) {
  // LDS tile [rows][64k] bf16, 16-row stripes of 2048B. Slot (row, kslot):
  //   ks=kslot>>2, kq=kslot&3
  //   byte = (row>>4)*2048 + (ks<<10) + (kq<<8) + ((((row&15)^kq^(ks<<2))&15)<<4)
  // v4-measured: 0 bank conflicts (write and frag-read).
  __shared__ __align__(16) char Asm[2][BM * BK * 2];   // 32 KB each
  __shared__ __align__(16) char Bsm[2][BN * BK * 2];   // 16 KB each

  const int bid = blockIdx.x;
  const int xcd = bid & 7;                 // dispatch round-robins XCDs by bid&7
  const int ord = bid >> 3;                // 0..31
  const int mtile = xcd * 4 + (ord >> 3);  // 4 XCD-exclusive m-panels per XCD
  const int ntile = ord & 7;
  const int brow = mtile * BM;
  const int bcol = ntile * BN;

  const int t = threadIdx.x;
  const int lane = t & 63;
  const int w = t >> 6;      // 0..7
  const int wm = w >> 1;     // 0..3 : 64-row quarter of BM=256
  const int wn = w & 1;      // 0..1 : 64-col half of BN=128

  // ---- staging: thread owns 16B k-slots. A: 2048 slots (256r x 8), 4/thread.
  //               B: 1024 slots (128r x 8), 2/thread. slot s -> row=s>>3, kslot=s&7.
  const int srow = t >> 3;   // 0..63
  const int kslot = t & 7;
  const int ks = kslot >> 2, kq = kslot & 3;

  const float* gA[4]; int woffA[4];
#pragma unroll
  for (int i = 0; i < 4; ++i) {
    int row = srow + i * 64;
    gA[i] = X + (size_t)(brow + row) * KD + kslot * 8;
    woffA[i] = (row >> 4) * 2048 + (ks << 10) + (kq << 8) +
               ((((row & 15) ^ kq ^ (ks << 2)) & 15) << 4);
  }
  const float* gB[2]; int woffB[2];
#pragma unroll
  for (int i = 0; i < 2; ++i) {
    int row = srow + i * 64;
    gB[i] = W + (size_t)(bcol + row) * KD + kslot * 8;
    woffB[i] = (row >> 4) * 2048 + (ks << 10) + (kq << 8) +
               ((((row & 15) ^ kq ^ (ks << 2)) & 15) << 4);
  }

  // fragment read offsets per ks (lane -> row=lane&15, kq=lane>>4), swizzle-mirrored
  int lb[2];
#pragma unroll
  for (int s = 0; s < 2; ++s)
    lb[s] = (s << 10) + ((lane >> 4) << 8) +
            ((((lane & 15) ^ (lane >> 4) ^ (s << 2)) & 15) << 4);

  // depth-2 prefetch register sets (constant-indexed, fully unrolled)
  f32x4 pa0[8], pb0[4], pa1[8], pb1[4];

#define LOADSET0(kt)                                                     \
  do {                                                                   \
    _Pragma("unroll") for (int i = 0; i < 4; ++i) {                      \
      const float* p = gA[i] + (size_t)(kt) * BK;                        \
      pa0[2*i] = *(const f32x4*)p; pa0[2*i+1] = *(const f32x4*)(p + 4);  \
    }                                                                    \
    _Pragma("unroll") for (int i = 0; i < 2; ++i) {                      \
      const float* p = gB[i] + (size_t)(kt) * BK;                        \
      pb0[2*i] = *(const f32x4*)p; pb0[2*i+1] = *(const f32x4*)(p + 4);  \
    }                                                                    \
  } while (0)
#define LOADSET1(kt)                                                     \
  do {                                                                   \
    _Pragma("unroll") for (int i = 0; i < 4; ++i) {                      \
      const float* p = gA[i] + (size_t)(kt) * BK;                        \
      pa1[2*i] = *(const f32x4*)p; pa1[2*i+1] = *(const f32x4*)(p + 4);  \
    }                                                                    \
    _Pragma("unroll") for (int i = 0; i < 2; ++i) {                      \
      const float* p = gB[i] + (size_t)(kt) * BK;                        \
      pb1[2*i] = *(const f32x4*)p; pb1[2*i+1] = *(const f32x4*)(p + 4);  \
    }                                                                    \
  } while (0)

#define WRITESET0(buf)                                                   \
  do {                                                                   \
    _Pragma("unroll") for (int i = 0; i < 4; ++i)                        \
        *(u16x8*)&Asm[buf][woffA[i]] = cvt8(pa0[2*i], pa0[2*i+1]);       \
    _Pragma("unroll") for (int i = 0; i < 2; ++i)                        \
        *(u16x8*)&Bsm[buf][woffB[i]] = cvt8(pb0[2*i], pb0[2*i+1]);       \
  } while (0)
#define WRITESET1(buf)                                                   \
  do {                                                                   \
    _Pragma("unroll") for (int i = 0; i < 4; ++i)                        \
        *(u16x8*)&Asm[buf][woffA[i]] = cvt8(pa1[2*i], pa1[2*i+1]);       \
    _Pragma("unroll") for (int i = 0; i < 2; ++i)                        \
        *(u16x8*)&Bsm[buf][woffB[i]] = cvt8(pb1[2*i], pb1[2*i+1]);       \
  } while (0)

  f32x4 acc[4][4] = {};

#define COMPUTE(buf)                                                            \
  do {                                                                          \
    _Pragma("unroll") for (int s = 0; s < 2; ++s) {                             \
      bf16x8 bf[4];                                                             \
      _Pragma("unroll") for (int n = 0; n < 4; ++n)                             \
        bf[n] = __builtin_bit_cast(bf16x8,                                      \
            *(const u16x8*)(&Bsm[buf][(wn * 4 + n) * 2048 + lb[s]]));           \
      bf16x8 am[4];                                                             \
      _Pragma("unroll") for (int m = 0; m < 4; ++m)                             \
        am[m] = __builtin_bit_cast(bf16x8,                                      \
            *(const u16x8*)(&Asm[buf][(wm * 4 + m) * 2048 + lb[s]]));           \
      __builtin_amdgcn_s_setprio(1);                                            \
      _Pragma("unroll") for (int m = 0; m < 4; ++m)                             \
        _Pragma("unroll") for (int n = 0; n < 4; ++n)                           \
          acc[m][n] = __builtin_amdgcn_mfma_f32_16x16x32_bf16(am[m], bf[n],     \
                                                              acc[m][n], 0, 0, 0); \
      __builtin_amdgcn_s_setprio(0);                                            \
    }                                                                           \
  } while (0)

  // ---- prologue: set0 <- tile0, set1 <- tile1, stage tile0 -> buf0
  LOADSET0(0);
  LOADSET1(1);
  WRITESET0(0);          // counted vmcnt (set1's 12 loads stay in flight)
  TILE_BARRIER();

  // ---- main loop: 2 tiles/iter; loads for tile kt+2 issued at tile kt,
  //      written at tile kt+1 (distance ~1 full tile > HBM miss latency)
#pragma unroll 1
  for (int kt2 = 0; kt2 < NT / 2; ++kt2) {
    // EVEN tile kt = 2*kt2 (reads buf0)
    if (kt2 < NT / 2 - 1) LOADSET0(2 * kt2 + 2);
    __builtin_amdgcn_sched_barrier(0);     // pin load-issue before cvt's vmcnt wait
    WRITESET1(1);                          // stage tile kt+1 (loaded 1 tile ago)
    COMPUTE(0);
    TILE_BARRIER();

    // ODD tile kt = 2*kt2+1 (reads buf1)
    if (kt2 < NT / 2 - 1) LOADSET1(2 * kt2 + 3);
    __builtin_amdgcn_sched_barrier(0);
    if (kt2 < NT / 2 - 1) WRITESET0(0);    // stage tile kt+2
    COMPUTE(1);
    TILE_BARRIER();
  }

  // ---- epilogue: C/D layout col = lane&15, row = (lane>>4)*4 + j  [m89, validated v5-v7]
  const int rbase = brow + wm * 64 + ((lane >> 4) << 2);
  const int cbase = bcol + wn * 64 + (lane & 15);
#pragma unroll
  for (int n = 0; n < 4; ++n) {
    const int col = cbase + n * 16;
    const float bv = Bv[col];
#pragma unroll
    for (int m = 0; m < 4; ++m) {
      const int row = rbase + m * 16;
#pragma unroll
      for (int j = 0; j < 4; ++j) {
        C[(size_t)(row + j) * ND + col] = acc[m][n][j] + bv;
      }
    }
  }
}

extern "C" void kernel_launch(void* const* d_in, const int* in_sizes, int n_in,
                              void* d_out, int out_size, void* d_ws, size_t ws_size,
                              hipStream_t stream) {
  const float* x = (const float*)d_in[0];   // [8192,1024] f32
  const float* W = (const float*)d_in[1];   // [1024,1024] f32
  const float* b = (const float*)d_in[2];   // [1024] f32
  float* out = (float*)d_out;               // [8192,1024] f32

  dim3 grid((MD / BM) * (ND / BN));   // 32 * 8 = 256 blocks = 1 per CU
  dim3 block(THREADS);
  hipLaunchKernelGGL(linear_mfma_v8, grid, block, 0, stream, x, W, b, out);
}